// Round 6
// baseline (765.579 us; speedup 1.0000x reference)
//
#include <hip/hip_runtime.h>
#include <math.h>

typedef _Float16 f16;
typedef f16 f16x8 __attribute__((ext_vector_type(8)));
typedef float f32x4 __attribute__((ext_vector_type(4)));

#define NB 4

// Transpose + convert conv weights: w[co][ci][9] f32 -> wt[k][co][ci] f16.
__global__ void __launch_bounds__(256)
wtrans_kernel(const float* __restrict__ w, f16* __restrict__ wt, int Co, int Cin) {
  int idx = blockIdx.x * 256 + threadIdx.x;
  int total = Co * Cin * 9;
  if (idx >= total) return;
  int k = idx % 9, t2 = idx / 9;
  int ci = t2 % Cin, co = t2 / Cin;
  wt[((size_t)k * Co + co) * Cin + ci] = (f16)w[idx];
}

// NCHW f32 -> NHWC f16 (Cin=1024 inputs). Block: one (b,h) x 64-channel chunk.
__global__ void __launch_bounds__(256)
nchw2nhwc(const float* __restrict__ in, f16* __restrict__ out) {
  __shared__ f16 s[64][66];
  const int t = threadIdx.x;
  const int bh = blockIdx.x, c0 = blockIdx.y * 64;
  const int b = bh >> 6, h = bh & 63;
  const int w = t & 63, cr = t >> 6;
  #pragma unroll
  for (int i = 0; i < 16; ++i) {
    int c = c0 + cr * 16 + i;
    s[cr * 16 + i][w] = (f16)in[(((size_t)b * 1024 + c) * 64 + h) * 64 + w];
  }
  __syncthreads();
  #pragma unroll
  for (int i = 0; i < 2; ++i) {
    int task = t + 256 * i;          // 512 = 8 octs x 64 w
    int oct = task & 7, w2 = task >> 3;
    f16x8 v;
    #pragma unroll
    for (int j = 0; j < 8; ++j) v[j] = s[oct * 8 + j][w2];
    *(f16x8*)(out + (((size_t)b * 64 + h) * 64 + w2) * 1024 + c0 + oct * 8) = v;
  }
}

// Implicit-GEMM 3x3 conv + BN + ReLU on NHWC f16, MFMA 16x16x32 f16, f32 acc.
// COW=2: block 128co x 64px(1 row), waves 2co x 2px. COW=1: 64co x 128px(2 rows).
// Wave = 64co x 32px = 4(m) x 2(n) frags. K = ci chunks(32) x 9 taps.
// Reg-staged double-buffered LDS; A-frags direct from global (L2-resident).
// in2: input = in - in2 (conv5). out==null: pooled per-(b,co,row) partials.
template<int COW>
__global__ void __launch_bounds__(256)
conv_mfma(const f16* __restrict__ in, const f16* __restrict__ in2,
          const f16* __restrict__ wt, const float* __restrict__ bn,
          f16* __restrict__ out, float* __restrict__ partial,
          int Cin, int Co) {
  constexpr int PW = 4 / COW;        // px waves
  constexpr int BCO = COW * 64;      // co per block
  constexpr int BROWS = PW / 2;      // image rows per block
  constexpr int SROWS = BROWS + 2;   // staged rows (halo)
  constexpr int TPB = 64 / BROWS;    // row-tiles per batch image
  constexpr int BCOP = BCO + 8;

  __shared__ __align__(16) f16 xs[2][SROWS][66][40];
  __shared__ float s_red[4][64];

  const int t = threadIdx.x;
  const int tile = blockIdx.x;
  const int b = tile / TPB;
  const int h0 = (tile % TPB) * BROWS;
  const int co_blk = blockIdx.y * BCO;
  const int wid = t >> 6, lane = t & 63;
  const int wm = wid / PW, wn = wid % PW;
  const int row_w = (wn * 32) >> 6, wcol = (wn * 32) & 63;
  const int l15 = lane & 15, lg = lane >> 4;
  const int koff = lg * 8;

  f32x4 acc[4][2];
  #pragma unroll
  for (int m = 0; m < 4; ++m)
    #pragma unroll
    for (int n = 0; n < 2; ++n)
      #pragma unroll
      for (int r = 0; r < 4; ++r) acc[m][n][r] = 0.f;

  const f16* inb = in + (size_t)b * Cin * 4096;
  const f16* inb2 = in2 ? in2 + (size_t)b * Cin * 4096 : nullptr;

  // staging lane map: 4 lanes cover one w's 32ci (64B), 16 w per instr
  const int wS = ((t >> 2) & 15) + (t >> 6) * 16;
  const int octS = t & 3;

  const f16* wA = wt + (size_t)(co_blk + wm * 64 + l15) * Cin + koff;
  const size_t wTap = (size_t)Co * Cin;
  const int NC = Cin >> 5;
  f16x8 breg[SROWS];

  auto load_stage = [&](int ci0) {
    #pragma unroll
    for (int r = 0; r < SROWS; ++r) {
      int gh = h0 - 1 + r;
      f16x8 v = {};
      if ((unsigned)gh < 64u) {
        size_t off = ((size_t)gh * 64 + wS) * Cin + ci0 + octS * 8;
        v = *(const f16x8*)(inb + off);
        if (inb2) { f16x8 v2 = *(const f16x8*)(inb2 + off); v = v - v2; }
      }
      breg[r] = v;
    }
  };
  auto write_stage = [&](int nb) {
    if (t < SROWS * 8) {             // zero w-halo columns 0 and 65
      int r = t >> 3, side = (t >> 2) & 1, oc = t & 3;
      f16x8 z = {};
      *(f16x8*)&xs[nb][r][side * 65][oc * 8] = z;
    }
    #pragma unroll
    for (int r = 0; r < SROWS; ++r)
      *(f16x8*)&xs[nb][r][wS + 1][octS * 8] = breg[r];
  };

  load_stage(0);
  write_stage(0);
  __syncthreads();

  for (int c = 0; c < NC; ++c) {
    const int cur = c & 1;
    const int ci0 = c << 5;
    if (c + 1 < NC) load_stage((c + 1) << 5);   // overlap with MFMA below
    #pragma unroll
    for (int tap = 0; tap < 9; ++tap) {
      const int dh = tap / 3 - 1, dw = tap % 3 - 1;
      const f16* wp = wA + (size_t)tap * wTap + ci0;
      f16x8 af[4];
      #pragma unroll
      for (int m = 0; m < 4; ++m) af[m] = *(const f16x8*)(wp + (size_t)(m * 16) * Cin);
      #pragma unroll
      for (int n = 0; n < 2; ++n) {
        const f16x8 bf = *(const f16x8*)&xs[cur][row_w + dh + 1][wcol + n * 16 + l15 + 1 + dw][koff];
        #pragma unroll
        for (int m = 0; m < 4; ++m)
          acc[m][n] = __builtin_amdgcn_mfma_f32_16x16x32_f16(af[m], bf, acc[m][n], 0, 0, 0);
      }
    }
    if (c + 1 < NC) write_stage(cur ^ 1);       // waits only on breg loads
    __syncthreads();
  }

  if (out) {
    // LDS transpose epilogue -> NHWC f16 coalesced stores
    f16* str = (f16*)xs;
    #pragma unroll
    for (int m = 0; m < 4; ++m)
      #pragma unroll
      for (int reg = 0; reg < 4; ++reg) {
        const int cwb = wm * 64 + m * 16 + lg * 4 + reg;
        const int co = co_blk + cwb;
        float scale = bn[co] / sqrtf(bn[3 * Co + co] + 1e-5f);
        float shift = bn[Co + co] - bn[2 * Co + co] * scale;
        #pragma unroll
        for (int n = 0; n < 2; ++n) {
          float val = fmaxf(fmaf(acc[m][n][reg], scale, shift), 0.f);
          str[(row_w * 64 + wcol + n * 16 + l15) * BCOP + cwb] = (f16)val;
        }
      }
    __syncthreads();
    #pragma unroll
    for (int i = 0; i < 4; ++i) {
      int task = t + 256 * i;                   // BROWS*64*(BCO/8) == 1024
      int oct = task % (BCO / 8);
      int rest = task / (BCO / 8);
      int w = rest & 63, row = rest >> 6;
      f16x8 v = *(const f16x8*)&str[(row * 64 + w) * BCOP + oct * 8];
      *(f16x8*)(out + (((size_t)(b * 64 + h0 + row) * 64) + w) * Co + co_blk + oct * 8) = v;
    }
  } else {
    // conv5: BN+ReLU -> per-(b,co,row-tile) pooled partials. Deterministic.
    #pragma unroll
    for (int m = 0; m < 4; ++m)
      #pragma unroll
      for (int reg = 0; reg < 4; ++reg) {
        const int cwb = wm * 64 + m * 16 + lg * 4 + reg;
        const int co = co_blk + cwb;
        float scale = bn[co] / sqrtf(bn[3 * Co + co] + 1e-5f);
        float shift = bn[Co + co] - bn[2 * Co + co] * scale;
        float s = fmaxf(fmaf(acc[m][0][reg], scale, shift), 0.f)
                + fmaxf(fmaf(acc[m][1][reg], scale, shift), 0.f);
        s += __shfl_xor(s, 1, 64);
        s += __shfl_xor(s, 2, 64);
        s += __shfl_xor(s, 4, 64);
        s += __shfl_xor(s, 8, 64);
        if (l15 == 0) s_red[wid][m * 16 + lg * 4 + reg] = s;
      }
    __syncthreads();
    if (COW == 2 && t < 128) {
      int wmx = t >> 6, c64 = t & 63;
      float v = s_red[wmx * 2 + 0][c64] + s_red[wmx * 2 + 1][c64];
      partial[((size_t)(b * Co) + co_blk + wmx * 64 + c64) * 64 + (tile % TPB)] = v;
    }
  }
}

// out[b,h,w,c] = sum_k atten[b,h,w,k] * x[b,h+dh,w+dw,c], NHWC f16, C=64.
__global__ void __launch_bounds__(256)
weighting_nhwc(const f16* __restrict__ x, const float* __restrict__ atten,
               f16* __restrict__ out) {
  __shared__ float s_a[64 * 81];
  const int h = blockIdx.x, b = blockIdx.y;
  const int t = threadIdx.x;
  for (int idx = t; idx < 64 * 81; idx += 256)
    s_a[idx] = atten[(size_t)((b * 64 + h) * 64) * 81 + idx];
  __syncthreads();

  const int w = t & 63, cg = t >> 6;   // thread: (w, 16-channel group)
  float acc[16];
  #pragma unroll
  for (int j = 0; j < 16; ++j) acc[j] = 0.f;

  for (int dh = -4; dh <= 4; ++dh) {
    int hh = h + dh;
    if ((unsigned)hh >= 64u) continue;
    #pragma unroll
    for (int dw = -4; dw <= 4; ++dw) {
      int ww = w + dw;
      if ((unsigned)ww >= 64u) continue;
      float a = s_a[w * 81 + (dh + 4) * 9 + (dw + 4)];
      const f16* xp = x + (((size_t)b * 64 + hh) * 64 + ww) * 64 + cg * 16;
      f16x8 v0 = *(const f16x8*)xp;
      f16x8 v1 = *(const f16x8*)(xp + 8);
      #pragma unroll
      for (int j = 0; j < 8; ++j) {
        acc[j]     = fmaf(a, (float)v0[j], acc[j]);
        acc[8 + j] = fmaf(a, (float)v1[j], acc[8 + j]);
      }
    }
  }
  f16x8 o0, o1;
  #pragma unroll
  for (int j = 0; j < 8; ++j) { o0[j] = (f16)acc[j]; o1[j] = (f16)acc[8 + j]; }
  f16* op = out + (((size_t)b * 64 + h) * 64 + w) * 64 + cg * 16;
  *(f16x8*)op = o0;
  *(f16x8*)(op + 8) = o1;
}

// partial[4][256][64] -> mean -> FC 256->10 -> 1. One block, wave per b.
__global__ void __launch_bounds__(256)
fc_kernel(const float* __restrict__ partial, const float* __restrict__ fw1,
          const float* __restrict__ fb1, const float* __restrict__ fw2,
          const float* __restrict__ fb2, float* __restrict__ outp) {
  const int t = threadIdx.x;
  const int b = t >> 6, lane = t & 63;
  float pooled[4];
  #pragma unroll
  for (int k = 0; k < 4; ++k) {
    int c = lane + 64 * k;
    float s = 0.f;
    #pragma unroll
    for (int p = 0; p < 64; ++p) s += partial[(size_t)(b * 256 + c) * 64 + p];
    pooled[k] = s * (1.f / 4096.f);
  }
  float o = 0.f;
  for (int i = 0; i < 10; ++i) {
    float d = 0.f;
    #pragma unroll
    for (int k = 0; k < 4; ++k) d += pooled[k] * fw1[i * 256 + lane + 64 * k];
    #pragma unroll
    for (int off = 32; off > 0; off >>= 1) d += __shfl_down(d, off, 64);
    o += (d + fb1[i]) * fw2[i];
  }
  if (lane == 0) outp[b] = o + fb2[0];
}

extern "C" void kernel_launch(void* const* d_in, const int* in_sizes, int n_in,
                              void* d_out, int out_size, void* d_ws, size_t ws_size,
                              hipStream_t stream) {
  const float* low_key    = (const float*)d_in[0];
  const float* low_nonkey = (const float*)d_in[1];
  const float* atten      = (const float*)d_in[2];
  const float* w1 = (const float*)d_in[3];  const float* bn1 = (const float*)d_in[4];
  const float* w2 = (const float*)d_in[5];  const float* bn2 = (const float*)d_in[6];
  const float* w3 = (const float*)d_in[7];  const float* bn3 = (const float*)d_in[8];
  const float* w4 = (const float*)d_in[9];  const float* bn4 = (const float*)d_in[10];
  const float* w5 = (const float*)d_in[11]; const float* bn5 = (const float*)d_in[12];
  const float* fw1 = (const float*)d_in[13]; const float* fb1 = (const float*)d_in[14];
  const float* fw2 = (const float*)d_in[15]; const float* fb2 = (const float*)d_in[16];

  f16* T   = (f16*)d_ws;          // 16,777,216 (transposed lk, then lnk)
  f16* X1  = T + 16777216;        // 4,194,304  (x1, later x4)
  f16* X2  = X1 + 4194304;        // 1,048,576  (x2)
  f16* X3  = X2 + 1048576;        // 1,048,576  (x3)
  f16* Y   = X3 + 1048576;        // 4,194,304  (y)
  f16* wt1 = Y + 4194304;         // 2,359,296
  f16* wt2 = wt1 + 2359296;       // 147,456
  f16* wt3 = wt2 + 147456;        // 147,456
  f16* wt4 = wt3 + 147456;        // 2,359,296
  f16* wt5 = wt4 + 2359296;       // 589,824
  float* P = (float*)(wt5 + 589824);  // 65,536 floats

  dim3 blk(256);
  wtrans_kernel<<<(256 * 1024 * 9 + 255) / 256, blk, 0, stream>>>(w1, wt1, 256, 1024);
  wtrans_kernel<<<(64 * 256 * 9 + 255) / 256, blk, 0, stream>>>(w2, wt2, 64, 256);
  wtrans_kernel<<<(256 * 64 * 9 + 255) / 256, blk, 0, stream>>>(w3, wt3, 256, 64);
  wtrans_kernel<<<(256 * 1024 * 9 + 255) / 256, blk, 0, stream>>>(w4, wt4, 256, 1024);
  wtrans_kernel<<<(256 * 256 * 9 + 255) / 256, blk, 0, stream>>>(w5, wt5, 256, 256);

  // lk -> NHWC f16
  nchw2nhwc<<<dim3(256, 16), blk, 0, stream>>>(low_key, T);
  // x1 = cbr(lk, w1)      [NHWC f16, C=256]
  conv_mfma<2><<<dim3(256, 2), blk, 0, stream>>>(T, nullptr, wt1, bn1, X1, nullptr, 1024, 256);
  // x2 = cbr(x1, w2)      [C=64]
  conv_mfma<1><<<dim3(128, 1), blk, 0, stream>>>(X1, nullptr, wt2, bn2, X2, nullptr, 256, 64);
  // x3 = weighting(x2)
  weighting_nhwc<<<dim3(64, NB), blk, 0, stream>>>(X2, atten, X3);
  // x4 = cbr(x3, w3)      (reuses X1)
  conv_mfma<2><<<dim3(256, 2), blk, 0, stream>>>(X3, nullptr, wt3, bn3, X1, nullptr, 64, 256);
  // lnk -> NHWC f16 (T free)
  nchw2nhwc<<<dim3(256, 16), blk, 0, stream>>>(low_nonkey, T);
  // y = cbr(lnk, w4)
  conv_mfma<2><<<dim3(256, 2), blk, 0, stream>>>(T, nullptr, wt4, bn4, Y, nullptr, 1024, 256);
  // z = cbr(x4 - y, w5) -> pooled partials
  conv_mfma<2><<<dim3(256, 2), blk, 0, stream>>>(X1, Y, wt5, bn5, nullptr, P, 256, 256);
  // mean -> FC -> FC
  fc_kernel<<<1, 256, 0, stream>>>(P, fw1, fb1, fw2, fb2, (float*)d_out);
}

// Round 7
// 344.698 us; speedup vs baseline: 2.2210x; 2.2210x over previous
//
#include <hip/hip_runtime.h>
#include <math.h>

typedef _Float16 f16;
typedef f16 f16x8 __attribute__((ext_vector_type(8)));
typedef float f32x4 __attribute__((ext_vector_type(4)));

#define NB 4

// Transpose + convert conv weights: w[co][ci][9] f32 -> wt[k][co][ci] f16.
__global__ void __launch_bounds__(256)
wtrans_kernel(const float* __restrict__ w, f16* __restrict__ wt, int Co, int Cin) {
  int idx = blockIdx.x * 256 + threadIdx.x;
  int total = Co * Cin * 9;
  if (idx >= total) return;
  int k = idx % 9, t2 = idx / 9;
  int ci = t2 % Cin, co = t2 / Cin;
  wt[((size_t)k * Co + co) * Cin + ci] = (f16)w[idx];
}

// NCHW f32 -> NHWC f16 (Cin=1024 inputs). Block: one (b,h) x 64-channel chunk.
__global__ void __launch_bounds__(256)
nchw2nhwc(const float* __restrict__ in, f16* __restrict__ out) {
  __shared__ f16 s[64][66];
  const int t = threadIdx.x;
  const int bh = blockIdx.x, c0 = blockIdx.y * 64;
  const int b = bh >> 6, h = bh & 63;
  const int w = t & 63, cr = t >> 6;
  #pragma unroll
  for (int i = 0; i < 16; ++i) {
    int c = c0 + cr * 16 + i;
    s[cr * 16 + i][w] = (f16)in[(((size_t)b * 1024 + c) * 64 + h) * 64 + w];
  }
  __syncthreads();
  #pragma unroll
  for (int i = 0; i < 2; ++i) {
    int task = t + 256 * i;          // 512 = 8 octs x 64 w
    int oct = task & 7, w2 = task >> 3;
    f16x8 v;
    #pragma unroll
    for (int j = 0; j < 8; ++j) v[j] = s[oct * 8 + j][w2];
    *(f16x8*)(out + (((size_t)b * 64 + h) * 64 + w2) * 1024 + c0 + oct * 8) = v;
  }
}

// Implicit-GEMM 3x3 conv + BN + ReLU, NHWC f16, MFMA 16x16x32, f32 acc.
// Block 256 thr = 4 px-waves; tile 64co x 128px (2 rows); wave = 64co x 32px
// = 4(m) x 2(n) frags. BOTH operands staged in LDS per 32-ci chunk:
// xs[4][66][40] input rows (halo), ws[9][64][32] weight slab. Register
// double-buffer: next chunk's global loads issue before current MFMA phase.
// in2: input = in - in2 (conv5). out==null: pooled per-(b,co,rowpair) partials.
__global__ void __launch_bounds__(256)
conv_mfma(const f16* __restrict__ in, const f16* __restrict__ in2,
          const f16* __restrict__ wt, const float* __restrict__ bn,
          f16* __restrict__ out, float* __restrict__ partial,
          int Cin, int Co) {
  __shared__ __align__(16) f16 xs[4][66][40];
  __shared__ __align__(16) f16 ws[9][64][32];
  __shared__ float s_red[4][64];

  const int t = threadIdx.x;
  const int tile = blockIdx.x;       // 128 = 4b x 32 row-pairs
  const int b = tile >> 5;
  const int h0 = (tile & 31) * 2;
  const int co_blk = blockIdx.y * 64;
  const int wid = t >> 6, lane = t & 63;
  const int row_w = wid >> 1, wcol = (wid & 1) * 32;
  const int l15 = lane & 15, lg = lane >> 4;
  const int koff = lg * 8;

  f32x4 acc[4][2];
  #pragma unroll
  for (int m = 0; m < 4; ++m)
    #pragma unroll
    for (int n = 0; n < 2; ++n)
      #pragma unroll
      for (int r = 0; r < 4; ++r) acc[m][n][r] = 0.f;

  const f16* inb = in + (size_t)b * Cin * 4096;
  const f16* inb2 = in2 ? in2 + (size_t)b * Cin * 4096 : nullptr;

  const int octS = t & 3, wS = (t >> 2) & 63;  // input staging map
  const int NC = Cin >> 5;
  f16x8 ireg[4], wreg[9];

  auto load_stage = [&](int ci0) {
    #pragma unroll
    for (int r = 0; r < 4; ++r) {
      int gh = h0 - 1 + r;
      f16x8 v = {};
      if ((unsigned)gh < 64u) {
        size_t off = ((size_t)gh * 64 + wS) * Cin + ci0 + octS * 8;
        v = *(const f16x8*)(inb + off);
        if (inb2) { f16x8 v2 = *(const f16x8*)(inb2 + off); v = v - v2; }
      }
      ireg[r] = v;
    }
    #pragma unroll
    for (int i = 0; i < 9; ++i) {   // 2304 slots = 4oct x 64co x 9tap
      int s = t + 256 * i;
      int oct = s & 3, co = (s >> 2) & 63, k = s >> 8;
      wreg[i] = *(const f16x8*)(wt + ((size_t)k * Co + co_blk + co) * Cin + ci0 + oct * 8);
    }
  };
  auto write_stage = [&]() {
    #pragma unroll
    for (int r = 0; r < 4; ++r)
      *(f16x8*)&xs[r][wS + 1][octS * 8] = ireg[r];
    #pragma unroll
    for (int i = 0; i < 9; ++i) {
      int s = t + 256 * i;
      int oct = s & 3, co = (s >> 2) & 63, k = s >> 8;
      *(f16x8*)&ws[k][co][oct * 8] = wreg[i];
    }
  };

  if (t < 32) {                      // zero w-halo columns once (never overwritten)
    int r = t >> 3, side = (t >> 2) & 1, oc = t & 3;
    f16x8 z = {};
    *(f16x8*)&xs[r][side * 65][oc * 8] = z;
  }
  load_stage(0);
  write_stage();
  __syncthreads();

  for (int c = 0; c < NC; ++c) {
    if (c + 1 < NC) load_stage((c + 1) << 5);   // globals overlap MFMA phase
    #pragma unroll
    for (int tap = 0; tap < 9; ++tap) {
      const int dh = tap / 3 - 1, dw = tap % 3 - 1;
      f16x8 af[4];
      #pragma unroll
      for (int m = 0; m < 4; ++m)
        af[m] = *(const f16x8*)&ws[tap][m * 16 + l15][koff];
      #pragma unroll
      for (int n = 0; n < 2; ++n) {
        const f16x8 bf = *(const f16x8*)&xs[row_w + dh + 1][wcol + n * 16 + l15 + 1 + dw][koff];
        #pragma unroll
        for (int m = 0; m < 4; ++m)
          acc[m][n] = __builtin_amdgcn_mfma_f32_16x16x32_f16(af[m], bf, acc[m][n], 0, 0, 0);
      }
    }
    __syncthreads();                  // all reads of chunk c done
    if (c + 1 < NC) write_stage();    // waits on own global loads only
    __syncthreads();                  // chunk c+1 visible
  }

  if (out) {
    // LDS transpose epilogue -> NHWC f16 coalesced stores (reuse xs as str)
    f16* str = (f16*)xs;              // [128 px][72] stride
    #pragma unroll
    for (int m = 0; m < 4; ++m)
      #pragma unroll
      for (int reg = 0; reg < 4; ++reg) {
        const int cwb = m * 16 + lg * 4 + reg;
        const int co = co_blk + cwb;
        float scale = bn[co] / sqrtf(bn[3 * Co + co] + 1e-5f);
        float shift = bn[Co + co] - bn[2 * Co + co] * scale;
        #pragma unroll
        for (int n = 0; n < 2; ++n) {
          float val = fmaxf(fmaf(acc[m][n][reg], scale, shift), 0.f);
          int px = row_w * 64 + wcol + n * 16 + l15;
          str[px * 72 + cwb] = (f16)val;
        }
      }
    __syncthreads();
    #pragma unroll
    for (int i = 0; i < 4; ++i) {     // 1024 = 8oct x 64w x 2rows
      int task = t + 256 * i;
      int oct = task & 7;
      int rest = task >> 3;
      int w = rest & 63, row = rest >> 6;
      f16x8 v = *(const f16x8*)&str[(row * 64 + w) * 72 + oct * 8];
      *(f16x8*)(out + (((size_t)(b * 64 + h0 + row) * 64) + w) * Co + co_blk + oct * 8) = v;
    }
  } else {
    // conv5: BN+ReLU -> pooled partials per (b,co,row-pair). Deterministic.
    #pragma unroll
    for (int m = 0; m < 4; ++m)
      #pragma unroll
      for (int reg = 0; reg < 4; ++reg) {
        const int cwb = m * 16 + lg * 4 + reg;
        const int co = co_blk + cwb;
        float scale = bn[co] / sqrtf(bn[3 * Co + co] + 1e-5f);
        float shift = bn[Co + co] - bn[2 * Co + co] * scale;
        float s = fmaxf(fmaf(acc[m][0][reg], scale, shift), 0.f)
                + fmaxf(fmaf(acc[m][1][reg], scale, shift), 0.f);
        s += __shfl_xor(s, 1, 64);   // sum over l15 (lane bits 0-3)
        s += __shfl_xor(s, 2, 64);
        s += __shfl_xor(s, 4, 64);
        s += __shfl_xor(s, 8, 64);
        if (l15 == 0) s_red[wid][cwb] = s;
      }
    __syncthreads();
    if (t < 64) {
      float v = s_red[0][t] + s_red[1][t] + s_red[2][t] + s_red[3][t];
      partial[((size_t)(b * 256) + co_blk + t) * 32 + (tile & 31)] = v;
    }
  }
}

// out[b,h,w,c] = sum_k atten[b,h,w,k] * x[b,h+dh,w+dw,c], NHWC f16, C=64.
__global__ void __launch_bounds__(256)
weighting_nhwc(const f16* __restrict__ x, const float* __restrict__ atten,
               f16* __restrict__ out) {
  __shared__ float s_a[64 * 81];
  const int h = blockIdx.x, b = blockIdx.y;
  const int t = threadIdx.x;
  for (int idx = t; idx < 64 * 81; idx += 256)
    s_a[idx] = atten[(size_t)((b * 64 + h) * 64) * 81 + idx];
  __syncthreads();

  const int w = t & 63, cg = t >> 6;   // thread: (w, 16-channel group)
  float acc[16];
  #pragma unroll
  for (int j = 0; j < 16; ++j) acc[j] = 0.f;

  for (int dh = -4; dh <= 4; ++dh) {
    int hh = h + dh;
    if ((unsigned)hh >= 64u) continue;
    #pragma unroll
    for (int dw = -4; dw <= 4; ++dw) {
      int ww = w + dw;
      if ((unsigned)ww >= 64u) continue;
      float a = s_a[w * 81 + (dh + 4) * 9 + (dw + 4)];
      const f16* xp = x + (((size_t)b * 64 + hh) * 64 + ww) * 64 + cg * 16;
      f16x8 v0 = *(const f16x8*)xp;
      f16x8 v1 = *(const f16x8*)(xp + 8);
      #pragma unroll
      for (int j = 0; j < 8; ++j) {
        acc[j]     = fmaf(a, (float)v0[j], acc[j]);
        acc[8 + j] = fmaf(a, (float)v1[j], acc[8 + j]);
      }
    }
  }
  f16x8 o0, o1;
  #pragma unroll
  for (int j = 0; j < 8; ++j) { o0[j] = (f16)acc[j]; o1[j] = (f16)acc[8 + j]; }
  f16* op = out + (((size_t)b * 64 + h) * 64 + w) * 64 + cg * 16;
  *(f16x8*)op = o0;
  *(f16x8*)(op + 8) = o1;
}

// partial[4][256][32] -> mean -> FC 256->10 -> 1. One block, wave per b.
__global__ void __launch_bounds__(256)
fc_kernel(const float* __restrict__ partial, const float* __restrict__ fw1,
          const float* __restrict__ fb1, const float* __restrict__ fw2,
          const float* __restrict__ fb2, float* __restrict__ outp) {
  const int t = threadIdx.x;
  const int b = t >> 6, lane = t & 63;
  float pooled[4];
  #pragma unroll
  for (int k = 0; k < 4; ++k) {
    int c = lane + 64 * k;
    float s = 0.f;
    #pragma unroll
    for (int p = 0; p < 32; ++p) s += partial[(size_t)(b * 256 + c) * 32 + p];
    pooled[k] = s * (1.f / 4096.f);
  }
  float o = 0.f;
  for (int i = 0; i < 10; ++i) {
    float d = 0.f;
    #pragma unroll
    for (int k = 0; k < 4; ++k) d += pooled[k] * fw1[i * 256 + lane + 64 * k];
    #pragma unroll
    for (int off = 32; off > 0; off >>= 1) d += __shfl_down(d, off, 64);
    o += (d + fb1[i]) * fw2[i];
  }
  if (lane == 0) outp[b] = o + fb2[0];
}

extern "C" void kernel_launch(void* const* d_in, const int* in_sizes, int n_in,
                              void* d_out, int out_size, void* d_ws, size_t ws_size,
                              hipStream_t stream) {
  const float* low_key    = (const float*)d_in[0];
  const float* low_nonkey = (const float*)d_in[1];
  const float* atten      = (const float*)d_in[2];
  const float* w1 = (const float*)d_in[3];  const float* bn1 = (const float*)d_in[4];
  const float* w2 = (const float*)d_in[5];  const float* bn2 = (const float*)d_in[6];
  const float* w3 = (const float*)d_in[7];  const float* bn3 = (const float*)d_in[8];
  const float* w4 = (const float*)d_in[9];  const float* bn4 = (const float*)d_in[10];
  const float* w5 = (const float*)d_in[11]; const float* bn5 = (const float*)d_in[12];
  const float* fw1 = (const float*)d_in[13]; const float* fb1 = (const float*)d_in[14];
  const float* fw2 = (const float*)d_in[15]; const float* fb2 = (const float*)d_in[16];

  f16* T   = (f16*)d_ws;          // 16,777,216 (transposed lk, then lnk)
  f16* X1  = T + 16777216;        // 4,194,304  (x1, later x4)
  f16* X2  = X1 + 4194304;        // 1,048,576  (x2)
  f16* X3  = X2 + 1048576;        // 1,048,576  (x3)
  f16* Y   = X3 + 1048576;        // 4,194,304  (y)
  f16* wt1 = Y + 4194304;         // 2,359,296
  f16* wt2 = wt1 + 2359296;       // 147,456
  f16* wt3 = wt2 + 147456;        // 147,456
  f16* wt4 = wt3 + 147456;        // 2,359,296
  f16* wt5 = wt4 + 2359296;       // 589,824
  float* P = (float*)(wt5 + 589824);  // 4*256*32 = 32768 floats

  dim3 blk(256);
  wtrans_kernel<<<(256 * 1024 * 9 + 255) / 256, blk, 0, stream>>>(w1, wt1, 256, 1024);
  wtrans_kernel<<<(64 * 256 * 9 + 255) / 256, blk, 0, stream>>>(w2, wt2, 64, 256);
  wtrans_kernel<<<(256 * 64 * 9 + 255) / 256, blk, 0, stream>>>(w3, wt3, 256, 64);
  wtrans_kernel<<<(256 * 1024 * 9 + 255) / 256, blk, 0, stream>>>(w4, wt4, 256, 1024);
  wtrans_kernel<<<(256 * 256 * 9 + 255) / 256, blk, 0, stream>>>(w5, wt5, 256, 256);

  // lk -> NHWC f16
  nchw2nhwc<<<dim3(256, 16), blk, 0, stream>>>(low_key, T);
  // x1 = cbr(lk, w1)      [NHWC f16, C=256]
  conv_mfma<<<dim3(128, 4), blk, 0, stream>>>(T, nullptr, wt1, bn1, X1, nullptr, 1024, 256);
  // x2 = cbr(x1, w2)      [C=64]
  conv_mfma<<<dim3(128, 1), blk, 0, stream>>>(X1, nullptr, wt2, bn2, X2, nullptr, 256, 64);
  // x3 = weighting(x2)
  weighting_nhwc<<<dim3(64, NB), blk, 0, stream>>>(X2, atten, X3);
  // x4 = cbr(x3, w3)      (reuses X1)
  conv_mfma<<<dim3(128, 4), blk, 0, stream>>>(X3, nullptr, wt3, bn3, X1, nullptr, 64, 256);
  // lnk -> NHWC f16 (T free)
  nchw2nhwc<<<dim3(256, 16), blk, 0, stream>>>(low_nonkey, T);
  // y = cbr(lnk, w4)
  conv_mfma<<<dim3(128, 4), blk, 0, stream>>>(T, nullptr, wt4, bn4, Y, nullptr, 1024, 256);
  // z = cbr(x4 - y, w5) -> pooled partials
  conv_mfma<<<dim3(128, 4), blk, 0, stream>>>(X1, Y, wt5, bn5, nullptr, P, 256, 256);
  // mean -> FC -> FC
  fc_kernel<<<1, 256, 0, stream>>>(P, fw1, fb1, fw2, fb2, (float*)d_out);
}

// Round 8
// 326.693 us; speedup vs baseline: 2.3434x; 1.0551x over previous
//
#include <hip/hip_runtime.h>
#include <math.h>

typedef _Float16 f16;
typedef f16 f16x4 __attribute__((ext_vector_type(4)));
typedef f16 f16x8 __attribute__((ext_vector_type(8)));
typedef float f32x4 __attribute__((ext_vector_type(4)));

#define NB 4

// Transpose + convert conv weights: w[co][ci][9] f32 -> wt[k][co][ci] f16.
// Output-linear indexing -> coalesced f16 stores (reads hit L1/L2).
__global__ void __launch_bounds__(256)
wtrans_kernel(const float* __restrict__ w, f16* __restrict__ wt, int Co, int Cin) {
  int idx = blockIdx.x * 256 + threadIdx.x;
  int total = Co * Cin * 9;
  if (idx >= total) return;
  int ci = idx % Cin, t2 = idx / Cin;
  int co = t2 % Co, k = t2 / Co;
  wt[idx] = (f16)w[((size_t)co * Cin + ci) * 9 + k];
}

// NCHW f32 -> NHWC f16 (Cin=1024 inputs). Block: one (b,h) x 64-channel chunk.
__global__ void __launch_bounds__(256)
nchw2nhwc(const float* __restrict__ in, f16* __restrict__ out) {
  __shared__ f16 s[64][66];
  const int t = threadIdx.x;
  const int bh = blockIdx.x, c0 = blockIdx.y * 64;
  const int b = bh >> 6, h = bh & 63;
  const int w = t & 63, cr = t >> 6;
  #pragma unroll
  for (int i = 0; i < 16; ++i) {
    int c = c0 + cr * 16 + i;
    s[cr * 16 + i][w] = (f16)in[(((size_t)b * 1024 + c) * 64 + h) * 64 + w];
  }
  __syncthreads();
  #pragma unroll
  for (int i = 0; i < 2; ++i) {
    int task = t + 256 * i;          // 512 = 8 octs x 64 w
    int oct = task & 7, w2 = task >> 3;
    f16x8 v;
    #pragma unroll
    for (int j = 0; j < 8; ++j) v[j] = s[oct * 8 + j][w2];
    *(f16x8*)(out + (((size_t)b * 64 + h) * 64 + w2) * 1024 + c0 + oct * 8) = v;
  }
}

// Implicit-GEMM 3x3 conv + BN + ReLU, NHWC f16, MFMA 16x16x32, f32 acc.
// Block 256 thr = 4 waves; tile 64co x 256px (4 image rows, wave = 1 row).
// Wave = 64co x 64px = 4(m) x 4(n) frags -> 8 LDS b128 reads per 16 MFMA.
// Per 32-ci chunk both operands staged in LDS: xs[6][66][40] (rows+halo),
// ws[9][64][32] (weight slab). Register double-buffer: next chunk's global
// loads issue before current MFMA phase; single LDS buffer, 2 barriers/chunk.
// in2: input = in - in2 (conv5). out==null: pooled per-(b,co,rowquad) partials.
__global__ void __launch_bounds__(256)
conv_mfma(const f16* __restrict__ in, const f16* __restrict__ in2,
          const f16* __restrict__ wt, const float* __restrict__ bn,
          f16* __restrict__ out, float* __restrict__ partial,
          int Cin, int Co) {
  __shared__ __align__(16) f16 xs[6][66][40];
  __shared__ __align__(16) f16 ws[9][64][32];
  __shared__ float s_red[4][64];

  const int t = threadIdx.x;
  const int tile = blockIdx.x;       // 64 = 4b x 16 row-quads
  const int b = tile >> 4;
  const int h0 = (tile & 15) * 4;
  const int co_blk = blockIdx.y * 64;
  const int wid = t >> 6, lane = t & 63;
  const int l15 = lane & 15, lg = lane >> 4;
  const int koff = lg * 8;

  f32x4 acc[4][4];                   // [m][n]
  #pragma unroll
  for (int m = 0; m < 4; ++m)
    #pragma unroll
    for (int n = 0; n < 4; ++n)
      #pragma unroll
      for (int r = 0; r < 4; ++r) acc[m][n][r] = 0.f;

  const f16* inb = in + (size_t)b * Cin * 4096;
  const f16* inb2 = in2 ? in2 + (size_t)b * Cin * 4096 : nullptr;

  const int wS = t >> 2, octS = t & 3;   // input staging: (w 0..63, ci-oct 0..3)
  const int NC = Cin >> 5;
  f16x8 ireg[6], wreg[9];

  auto load_stage = [&](int ci0) {
    #pragma unroll
    for (int r = 0; r < 6; ++r) {
      int gh = h0 - 1 + r;
      f16x8 v = {};
      if ((unsigned)gh < 64u) {
        size_t off = ((size_t)gh * 64 + wS) * Cin + ci0 + octS * 8;
        v = *(const f16x8*)(inb + off);
        if (inb2) { f16x8 v2 = *(const f16x8*)(inb2 + off); v = v - v2; }
      }
      ireg[r] = v;
    }
    #pragma unroll
    for (int i = 0; i < 9; ++i) {    // 2304 slots = 4oct x 64co x 9tap
      int s = t + 256 * i;
      int oct = s & 3, co = (s >> 2) & 63, k = s >> 8;
      wreg[i] = *(const f16x8*)(wt + ((size_t)k * Co + co_blk + co) * Cin + ci0 + oct * 8);
    }
  };
  auto write_stage = [&]() {
    #pragma unroll
    for (int r = 0; r < 6; ++r)
      *(f16x8*)&xs[r][wS + 1][octS * 8] = ireg[r];
    #pragma unroll
    for (int i = 0; i < 9; ++i) {
      int s = t + 256 * i;
      int oct = s & 3, co = (s >> 2) & 63, k = s >> 8;
      *(f16x8*)&ws[k][co][oct * 8] = wreg[i];
    }
  };

  if (t < 48) {                      // zero w-halo columns once (never rewritten)
    int r = t >> 3, side = (t >> 2) & 1, oc = t & 3;
    f16x8 z = {};
    *(f16x8*)&xs[r][side * 65][oc * 8] = z;
  }
  load_stage(0);
  write_stage();
  __syncthreads();

  for (int c = 0; c < NC; ++c) {
    if (c + 1 < NC) load_stage((c + 1) << 5);   // globals overlap MFMA phase
    #pragma unroll
    for (int tap = 0; tap < 9; ++tap) {
      const int dh = tap / 3 - 1, dw = tap % 3 - 1;
      f16x8 af[4];
      #pragma unroll
      for (int m = 0; m < 4; ++m)
        af[m] = *(const f16x8*)&ws[tap][m * 16 + l15][koff];
      #pragma unroll
      for (int n = 0; n < 4; ++n) {
        const f16x8 bf = *(const f16x8*)&xs[wid + dh + 1][n * 16 + l15 + 1 + dw][koff];
        #pragma unroll
        for (int m = 0; m < 4; ++m)
          acc[m][n] = __builtin_amdgcn_mfma_f32_16x16x32_f16(af[m], bf, acc[m][n], 0, 0, 0);
      }
    }
    __syncthreads();                  // all reads of chunk c done
    if (c + 1 < NC) write_stage();    // waits on own global loads only
    __syncthreads();                  // chunk c+1 visible
  }

  if (out) {
    // Direct NHWC stores: lane holds 4 consecutive co per (m,n) -> f16x4.
    #pragma unroll
    for (int m = 0; m < 4; ++m) {
      float sc[4], sh[4];
      #pragma unroll
      for (int reg = 0; reg < 4; ++reg) {
        int co = co_blk + m * 16 + lg * 4 + reg;
        sc[reg] = bn[co] / sqrtf(bn[3 * Co + co] + 1e-5f);
        sh[reg] = bn[Co + co] - bn[2 * Co + co] * sc[reg];
      }
      #pragma unroll
      for (int n = 0; n < 4; ++n) {
        f16x4 v;
        #pragma unroll
        for (int reg = 0; reg < 4; ++reg)
          v[reg] = (f16)fmaxf(fmaf(acc[m][n][reg], sc[reg], sh[reg]), 0.f);
        *(f16x4*)(out + ((size_t)(b * 64 + h0 + wid) * 64 + n * 16 + l15) * Co
                      + co_blk + m * 16 + lg * 4) = v;
      }
    }
  } else {
    // conv5: BN+ReLU -> pooled partials per (b,co,row-quad). Deterministic.
    #pragma unroll
    for (int m = 0; m < 4; ++m)
      #pragma unroll
      for (int reg = 0; reg < 4; ++reg) {
        int co = co_blk + m * 16 + lg * 4 + reg;
        float sc = bn[co] / sqrtf(bn[3 * Co + co] + 1e-5f);
        float sh = bn[Co + co] - bn[2 * Co + co] * sc;
        float s = 0.f;
        #pragma unroll
        for (int n = 0; n < 4; ++n)
          s += fmaxf(fmaf(acc[m][n][reg], sc, sh), 0.f);
        s += __shfl_xor(s, 1, 64);   // reduce over l15 (lane bits 0-3)
        s += __shfl_xor(s, 2, 64);
        s += __shfl_xor(s, 4, 64);
        s += __shfl_xor(s, 8, 64);
        if (l15 == 0) s_red[wid][m * 16 + lg * 4 + reg] = s;
      }
    __syncthreads();
    if (t < 64) {
      float v = s_red[0][t] + s_red[1][t] + s_red[2][t] + s_red[3][t];
      partial[((size_t)b * Co + co_blk + t) * 16 + (tile & 15)] = v;
    }
  }
}

// out[b,h,w,c] = sum_k atten[b,h,w,k] * x[b,h+dh,w+dw,c], NHWC f16, C=64.
__global__ void __launch_bounds__(256)
weighting_nhwc(const f16* __restrict__ x, const float* __restrict__ atten,
               f16* __restrict__ out) {
  __shared__ float s_a[64 * 81];
  const int h = blockIdx.x, b = blockIdx.y;
  const int t = threadIdx.x;
  for (int idx = t; idx < 64 * 81; idx += 256)
    s_a[idx] = atten[(size_t)((b * 64 + h) * 64) * 81 + idx];
  __syncthreads();

  const int w = t & 63, cg = t >> 6;   // thread: (w, 16-channel group)
  float acc[16];
  #pragma unroll
  for (int j = 0; j < 16; ++j) acc[j] = 0.f;

  for (int dh = -4; dh <= 4; ++dh) {
    int hh = h + dh;
    if ((unsigned)hh >= 64u) continue;
    #pragma unroll
    for (int dw = -4; dw <= 4; ++dw) {
      int ww = w + dw;
      if ((unsigned)ww >= 64u) continue;
      float a = s_a[w * 81 + (dh + 4) * 9 + (dw + 4)];
      const f16* xp = x + (((size_t)b * 64 + hh) * 64 + ww) * 64 + cg * 16;
      f16x8 v0 = *(const f16x8*)xp;
      f16x8 v1 = *(const f16x8*)(xp + 8);
      #pragma unroll
      for (int j = 0; j < 8; ++j) {
        acc[j]     = fmaf(a, (float)v0[j], acc[j]);
        acc[8 + j] = fmaf(a, (float)v1[j], acc[8 + j]);
      }
    }
  }
  f16x8 o0, o1;
  #pragma unroll
  for (int j = 0; j < 8; ++j) { o0[j] = (f16)acc[j]; o1[j] = (f16)acc[8 + j]; }
  f16* op = out + (((size_t)b * 64 + h) * 64 + w) * 64 + cg * 16;
  *(f16x8*)op = o0;
  *(f16x8*)(op + 8) = o1;
}

// partial[4][256][16] -> mean -> FC 256->10 -> 1. One block, wave per b.
__global__ void __launch_bounds__(256)
fc_kernel(const float* __restrict__ partial, const float* __restrict__ fw1,
          const float* __restrict__ fb1, const float* __restrict__ fw2,
          const float* __restrict__ fb2, float* __restrict__ outp) {
  const int t = threadIdx.x;
  const int b = t >> 6, lane = t & 63;
  float pooled[4];
  #pragma unroll
  for (int k = 0; k < 4; ++k) {
    int c = lane + 64 * k;
    float s = 0.f;
    #pragma unroll
    for (int p = 0; p < 16; ++p) s += partial[(size_t)(b * 256 + c) * 16 + p];
    pooled[k] = s * (1.f / 4096.f);
  }
  float o = 0.f;
  for (int i = 0; i < 10; ++i) {
    float d = 0.f;
    #pragma unroll
    for (int k = 0; k < 4; ++k) d += pooled[k] * fw1[i * 256 + lane + 64 * k];
    #pragma unroll
    for (int off = 32; off > 0; off >>= 1) d += __shfl_down(d, off, 64);
    o += (d + fb1[i]) * fw2[i];
  }
  if (lane == 0) outp[b] = o + fb2[0];
}

extern "C" void kernel_launch(void* const* d_in, const int* in_sizes, int n_in,
                              void* d_out, int out_size, void* d_ws, size_t ws_size,
                              hipStream_t stream) {
  const float* low_key    = (const float*)d_in[0];
  const float* low_nonkey = (const float*)d_in[1];
  const float* atten      = (const float*)d_in[2];
  const float* w1 = (const float*)d_in[3];  const float* bn1 = (const float*)d_in[4];
  const float* w2 = (const float*)d_in[5];  const float* bn2 = (const float*)d_in[6];
  const float* w3 = (const float*)d_in[7];  const float* bn3 = (const float*)d_in[8];
  const float* w4 = (const float*)d_in[9];  const float* bn4 = (const float*)d_in[10];
  const float* w5 = (const float*)d_in[11]; const float* bn5 = (const float*)d_in[12];
  const float* fw1 = (const float*)d_in[13]; const float* fb1 = (const float*)d_in[14];
  const float* fw2 = (const float*)d_in[15]; const float* fb2 = (const float*)d_in[16];

  f16* T   = (f16*)d_ws;          // 16,777,216 (transposed lk, then lnk)
  f16* X1  = T + 16777216;        // 4,194,304  (x1, later x4)
  f16* X2  = X1 + 4194304;        // 1,048,576  (x2)
  f16* X3  = X2 + 1048576;        // 1,048,576  (x3)
  f16* Y   = X3 + 1048576;        // 4,194,304  (y)
  f16* wt1 = Y + 4194304;         // 2,359,296
  f16* wt2 = wt1 + 2359296;       // 147,456
  f16* wt3 = wt2 + 147456;        // 147,456
  f16* wt4 = wt3 + 147456;        // 2,359,296
  f16* wt5 = wt4 + 2359296;       // 589,824
  float* P = (float*)(wt5 + 589824);  // 4*256*16 floats

  dim3 blk(256);
  wtrans_kernel<<<(256 * 1024 * 9 + 255) / 256, blk, 0, stream>>>(w1, wt1, 256, 1024);
  wtrans_kernel<<<(64 * 256 * 9 + 255) / 256, blk, 0, stream>>>(w2, wt2, 64, 256);
  wtrans_kernel<<<(256 * 64 * 9 + 255) / 256, blk, 0, stream>>>(w3, wt3, 256, 64);
  wtrans_kernel<<<(256 * 1024 * 9 + 255) / 256, blk, 0, stream>>>(w4, wt4, 256, 1024);
  wtrans_kernel<<<(256 * 256 * 9 + 255) / 256, blk, 0, stream>>>(w5, wt5, 256, 256);

  // lk -> NHWC f16
  nchw2nhwc<<<dim3(256, 16), blk, 0, stream>>>(low_key, T);
  // x1 = cbr(lk, w1)      [NHWC f16, C=256]
  conv_mfma<<<dim3(64, 4), blk, 0, stream>>>(T, nullptr, wt1, bn1, X1, nullptr, 1024, 256);
  // x2 = cbr(x1, w2)      [C=64]
  conv_mfma<<<dim3(64, 1), blk, 0, stream>>>(X1, nullptr, wt2, bn2, X2, nullptr, 256, 64);
  // x3 = weighting(x2)
  weighting_nhwc<<<dim3(64, NB), blk, 0, stream>>>(X2, atten, X3);
  // x4 = cbr(x3, w3)      (reuses X1)
  conv_mfma<<<dim3(64, 4), blk, 0, stream>>>(X3, nullptr, wt3, bn3, X1, nullptr, 64, 256);
  // lnk -> NHWC f16 (T free)
  nchw2nhwc<<<dim3(256, 16), blk, 0, stream>>>(low_nonkey, T);
  // y = cbr(lnk, w4)
  conv_mfma<<<dim3(64, 4), blk, 0, stream>>>(T, nullptr, wt4, bn4, Y, nullptr, 1024, 256);
  // z = cbr(x4 - y, w5) -> pooled partials
  conv_mfma<<<dim3(64, 4), blk, 0, stream>>>(X1, Y, wt5, bn5, nullptr, P, 256, 256);
  // mean -> FC -> FC
  fc_kernel<<<1, 256, 0, stream>>>(P, fw1, fb1, fw2, fb2, (float*)d_out);
}